// Round 3
// baseline (407.533 us; speedup 1.0000x reference)
//
#include <hip/hip_runtime.h>
#include <cstdint>

// ---------------- CSR build ----------------

__global__ __launch_bounds__(256) void k_hist(const int* __restrict__ ei,
        int E, int E2, int* __restrict__ deg) {
    int e = blockIdx.x * 256 + threadIdx.x;
    if (e >= E2) return;
    int dst = (e < E) ? ei[E + e] : (e - E);
    atomicAdd(&deg[dst], 1);
}

__global__ __launch_bounds__(1024) void k_scan(const int* __restrict__ deg,
        int* __restrict__ row_start, int N) {
    __shared__ int buf[1024];
    int t = threadIdx.x;
    int chunk = (N + 1023) >> 10;
    int lo = t * chunk, hi = min(lo + chunk, N);
    int s = 0;
    for (int i = lo; i < hi; ++i) s += deg[i];
    buf[t] = s;
    __syncthreads();
    for (int off = 1; off < 1024; off <<= 1) {
        int v = (t >= off) ? buf[t - off] : 0;
        __syncthreads();
        buf[t] += v;
        __syncthreads();
    }
    int run = buf[t] - s;  // exclusive prefix
    for (int i = lo; i < hi; ++i) { row_start[i] = run; run += deg[i]; }
    if (t == 1023) row_start[N] = buf[1023];
}

__global__ __launch_bounds__(256) void k_scatter(const int* __restrict__ ei,
        int E, int E2, const int* __restrict__ row_start, int* __restrict__ cursor,
        int* __restrict__ csr_src) {
    int e = blockIdx.x * 256 + threadIdx.x;
    if (e >= E2) return;
    int src, dst;
    if (e < E) { src = ei[e]; dst = ei[E + e]; }
    else       { src = e - E; dst = src; }
    int pos = row_start[dst] + atomicAdd(&cursor[dst], 1);
    csr_src[pos] = src;
}

// ---------------- GEMM1: [N,512] @ [512,64] -> h1 [N,64] ----------------
// block 256, tile 64 rows x 64 cols, BK=16; thread computes 4x4 outputs.

__global__ __launch_bounds__(256) void k_gemm1(const float* __restrict__ x,
        const float* __restrict__ W, float* __restrict__ h1, int N) {
    __shared__ float xs[64][17];
    __shared__ float ws[16][64];
    int t = threadIdx.x;
    int row0 = blockIdx.x * 64;
    int c0 = (t & 15) * 4;
    int r0 = (t >> 4) * 4;
    int lr = t >> 2, lf = t & 3;           // x staging: row lr, float4 slot lf
    int wr = t >> 4, wc = (t & 15) * 4;    // W staging
    float4 acc[4] = {};
    for (int k0 = 0; k0 < 512; k0 += 16) {
        float4 xv = make_float4(0.f, 0.f, 0.f, 0.f);
        int grow = row0 + lr;
        if (grow < N) xv = *(const float4*)(x + (size_t)grow * 512 + k0 + lf * 4);
        float4 wv = *(const float4*)(W + (size_t)(k0 + wr) * 64 + wc);
        __syncthreads();
        xs[lr][lf * 4 + 0] = xv.x; xs[lr][lf * 4 + 1] = xv.y;
        xs[lr][lf * 4 + 2] = xv.z; xs[lr][lf * 4 + 3] = xv.w;
        *(float4*)&ws[wr][wc] = wv;
        __syncthreads();
        #pragma unroll
        for (int kk = 0; kk < 16; ++kk) {
            float4 w4 = *(const float4*)&ws[kk][c0];
            #pragma unroll
            for (int i = 0; i < 4; ++i) {
                float a = xs[r0 + i][kk];
                acc[i].x += a * w4.x; acc[i].y += a * w4.y;
                acc[i].z += a * w4.z; acc[i].w += a * w4.w;
            }
        }
    }
    #pragma unroll
    for (int i = 0; i < 4; ++i) {
        int row = row0 + r0 + i;
        if (row < N) *(float4*)(h1 + (size_t)row * 64 + c0) = acc[i];
    }
}

// ---------------- GEMM2: [N,64] @ [64,128] -> h2 [N,128] ----------------

__global__ __launch_bounds__(256) void k_gemm2(const float* __restrict__ hin,
        const float* __restrict__ W, float* __restrict__ h2, int N) {
    __shared__ float xs[64][65];
    __shared__ float ws[64][128];
    int t = threadIdx.x;
    int row0 = blockIdx.x * 64;
    #pragma unroll
    for (int u = 0; u < 4; ++u) {
        int idx = t + u * 256;       // float4 index into 64x64 tile
        int r = idx >> 4, f = idx & 15;
        int grow = row0 + r;
        float4 v = make_float4(0.f, 0.f, 0.f, 0.f);
        if (grow < N) v = *(const float4*)(hin + (size_t)grow * 64 + f * 4);
        xs[r][f * 4 + 0] = v.x; xs[r][f * 4 + 1] = v.y;
        xs[r][f * 4 + 2] = v.z; xs[r][f * 4 + 3] = v.w;
    }
    #pragma unroll
    for (int u = 0; u < 8; ++u) {
        int idx = t + u * 256;
        int kr = idx >> 5, c4 = (idx & 31) * 4;
        *(float4*)&ws[kr][c4] = *(const float4*)(W + (size_t)kr * 128 + c4);
    }
    __syncthreads();
    int c0 = (t & 15) * 8;
    int r0 = (t >> 4) * 4;
    float4 acc[4][2] = {};
    #pragma unroll 8
    for (int kk = 0; kk < 64; ++kk) {
        float4 w0 = *(const float4*)&ws[kk][c0];
        float4 w1 = *(const float4*)&ws[kk][c0 + 4];
        #pragma unroll
        for (int i = 0; i < 4; ++i) {
            float a = xs[r0 + i][kk];
            acc[i][0].x += a * w0.x; acc[i][0].y += a * w0.y;
            acc[i][0].z += a * w0.z; acc[i][0].w += a * w0.w;
            acc[i][1].x += a * w1.x; acc[i][1].y += a * w1.y;
            acc[i][1].z += a * w1.z; acc[i][1].w += a * w1.w;
        }
    }
    #pragma unroll
    for (int i = 0; i < 4; ++i) {
        int row = row0 + r0 + i;
        if (row < N) {
            *(float4*)(h2 + (size_t)row * 128 + c0) = acc[i][0];
            *(float4*)(h2 + (size_t)row * 128 + c0 + 4) = acc[i][1];
        }
    }
}

// ---------------- attention coefficients ----------------

__global__ __launch_bounds__(256) void k_att1(const float* __restrict__ h1,
        const float* __restrict__ att_src, const float* __restrict__ att_dst,
        float* __restrict__ a_s, float* __restrict__ a_d, int NH) {
    int i = blockIdx.x * 256 + threadIdx.x;
    if (i >= NH) return;
    int h = i & 7;
    const float* hp = h1 + (size_t)i * 8;
    const float* sp = att_src + h * 8;
    const float* dp = att_dst + h * 8;
    float s = 0.f, d = 0.f;
    #pragma unroll
    for (int c = 0; c < 8; ++c) { float v = hp[c]; s += v * sp[c]; d += v * dp[c]; }
    a_s[i] = s; a_d[i] = d;
}

__global__ __launch_bounds__(256) void k_att2(const float* __restrict__ h2,
        const float* __restrict__ att_src, const float* __restrict__ att_dst,
        float* __restrict__ a_s, float* __restrict__ a_d, int N) {
    int node = blockIdx.x * 4 + (threadIdx.x >> 6);
    int lane = threadIdx.x & 63;
    if (node >= N) return;
    const float* hp = h2 + (size_t)node * 128;
    float v0 = hp[lane], v1 = hp[lane + 64];
    float s = v0 * att_src[lane] + v1 * att_src[lane + 64];
    float d = v0 * att_dst[lane] + v1 * att_dst[lane + 64];
    #pragma unroll
    for (int off = 32; off >= 1; off >>= 1) {
        s += __shfl_xor(s, off, 64);
        d += __shfl_xor(d, off, 64);
    }
    if (lane == 0) { a_s[node] = s; a_d[node] = d; }
}

// ---------------- GAT aggregation, layer 1 (H=8, C=8) + bias + ELU ----------------
// one 64-lane wave per dst node; lane = output channel; h = lane>>3.

__global__ __launch_bounds__(256) void k_gat1(
        const int* __restrict__ row_start, const int* __restrict__ csr_src,
        const float* __restrict__ h1, const float* __restrict__ a_src,
        const float* __restrict__ a_dst, const float* __restrict__ bias,
        float* __restrict__ outp, int N) {
    int node = blockIdx.x * 4 + (threadIdx.x >> 6);
    int lane = threadIdx.x & 63;
    if (node >= N) return;
    int h = lane >> 3;
    int start = row_start[node], end = row_start[node + 1];

    float ad8[8];
    #pragma unroll
    for (int hh = 0; hh < 8; ++hh) ad8[hh] = a_dst[node * 8 + hh];

    // lane-parallel denominator over edges, all 8 heads per lane
    float dh[8] = {0.f,0.f,0.f,0.f,0.f,0.f,0.f,0.f};
    for (int base = start; base < end; base += 64) {
        int idx = base + lane;
        if (idx < end) {
            int s = csr_src[idx];
            const float* ap = a_src + (size_t)s * 8;
            #pragma unroll
            for (int hh = 0; hh < 8; ++hh) {
                float al = ap[hh] + ad8[hh];
                al = al > 0.f ? al : 0.2f * al;
                dh[hh] += __expf(al);
            }
        }
    }
    #pragma unroll
    for (int hh = 0; hh < 8; ++hh) {
        #pragma unroll
        for (int off = 32; off >= 1; off >>= 1) dh[hh] += __shfl_xor(dh[hh], off, 64);
    }
    float den = dh[0];
    #pragma unroll
    for (int hh = 1; hh < 8; ++hh) den = (h == hh) ? dh[hh] : den;
    float adst = ad8[0];
    #pragma unroll
    for (int hh = 1; hh < 8; ++hh) adst = (h == hh) ? ad8[hh] : adst;
    float inv = 1.f / (den + 1e-16f);

    // weighted accumulate: edge-serial, lane = channel
    float acc = 0.f;
    for (int base = start; base < end; base += 64) {
        int idx = base + lane;
        int sv = (idx < end) ? csr_src[idx] : 0;
        int cnt = min(64, end - base);
        for (int j = 0; j < cnt; ++j) {
            int s = __shfl(sv, j, 64);
            float al = a_src[(size_t)s * 8 + h] + adst;
            al = al > 0.f ? al : 0.2f * al;
            float w = __expf(al) * inv;
            acc += h1[(size_t)s * 64 + lane] * w;
        }
    }
    float v = acc + bias[lane];
    outp[(size_t)node * 64 + lane] = v > 0.f ? v : __expf(v) - 1.f;  // ELU
}

// ---------------- GAT aggregation, layer 2 (H=1, C=128) + bias ----------------

__global__ __launch_bounds__(256) void k_gat2(
        const int* __restrict__ row_start, const int* __restrict__ csr_src,
        const float* __restrict__ h2, const float* __restrict__ a_src,
        const float* __restrict__ a_dst, const float* __restrict__ bias,
        float* __restrict__ outp, int N) {
    int node = blockIdx.x * 4 + (threadIdx.x >> 6);
    int lane = threadIdx.x & 63;
    if (node >= N) return;
    int start = row_start[node], end = row_start[node + 1];
    float adst = a_dst[node];

    float dsum = 0.f;
    for (int base = start; base < end; base += 64) {
        int idx = base + lane;
        if (idx < end) {
            float al = a_src[csr_src[idx]] + adst;
            al = al > 0.f ? al : 0.2f * al;
            dsum += __expf(al);
        }
    }
    #pragma unroll
    for (int off = 32; off >= 1; off >>= 1) dsum += __shfl_xor(dsum, off, 64);
    float inv = 1.f / (dsum + 1e-16f);

    float acc0 = 0.f, acc1 = 0.f;
    for (int base = start; base < end; base += 64) {
        int idx = base + lane;
        int sv = (idx < end) ? csr_src[idx] : 0;
        int cnt = min(64, end - base);
        for (int j = 0; j < cnt; ++j) {
            int s = __shfl(sv, j, 64);
            float al = a_src[s] + adst;
            al = al > 0.f ? al : 0.2f * al;
            float w = __expf(al) * inv;
            const float* hp = h2 + (size_t)s * 128;
            acc0 += hp[lane] * w;
            acc1 += hp[lane + 64] * w;
        }
    }
    outp[(size_t)node * 128 + lane]      = acc0 + bias[lane];
    outp[(size_t)node * 128 + lane + 64] = acc1 + bias[lane + 64];
}

// ---------------- launcher ----------------

extern "C" void kernel_launch(void* const* d_in, const int* in_sizes, int n_in,
                              void* d_out, int out_size, void* d_ws, size_t ws_size,
                              hipStream_t stream) {
    const float* x   = (const float*)d_in[0];
    const int*   ei  = (const int*)d_in[1];     // integer inputs arrive as int32
    const float* W1  = (const float*)d_in[2];
    const float* as1 = (const float*)d_in[3];
    const float* ad1 = (const float*)d_in[4];
    const float* b1  = (const float*)d_in[5];
    const float* W2  = (const float*)d_in[6];
    const float* as2 = (const float*)d_in[7];
    const float* ad2 = (const float*)d_in[8];
    const float* b2  = (const float*)d_in[9];
    int N  = in_sizes[0] / 512;
    int E  = in_sizes[1] / 2;
    int E2 = E + N;

    char* wsp = (char*)d_ws;
    size_t off = 0;
    auto alloc = [&](size_t bytes) {
        char* p = wsp + off;
        off = (off + bytes + 255) & ~(size_t)255;
        return p;
    };
    float* h1   = (float*)alloc((size_t)N * 64 * 4);
    float* hmid = (float*)alloc((size_t)N * 64 * 4);
    float* h2   = (float*)alloc((size_t)N * 128 * 4);
    float* a1s  = (float*)alloc((size_t)N * 8 * 4);
    float* a1d  = (float*)alloc((size_t)N * 8 * 4);
    float* a2s  = (float*)alloc((size_t)N * 4);
    float* a2d  = (float*)alloc((size_t)N * 4);
    int* deg    = (int*)alloc((size_t)2 * N * 4);  // deg | cursor
    int* cursor = deg + N;
    int* row_start = (int*)alloc((size_t)(N + 1) * 4);
    int* csr_src   = (int*)alloc((size_t)E2 * 4);
    (void)ws_size; (void)n_in; (void)out_size;

    hipMemsetAsync(deg, 0, (size_t)2 * N * 4, stream);
    int eb = (E2 + 255) / 256;
    k_hist<<<eb, 256, 0, stream>>>(ei, E, E2, deg);
    k_scan<<<1, 1024, 0, stream>>>(deg, row_start, N);
    k_scatter<<<eb, 256, 0, stream>>>(ei, E, E2, row_start, cursor, csr_src);

    int gb = (N + 63) / 64;
    k_gemm1<<<gb, 256, 0, stream>>>(x, W1, h1, N);
    k_att1<<<(N * 8 + 255) / 256, 256, 0, stream>>>(h1, as1, ad1, a1s, a1d, N * 8);
    int nb4 = (N + 3) / 4;
    k_gat1<<<nb4, 256, 0, stream>>>(row_start, csr_src, h1, a1s, a1d, b1, hmid, N);
    k_gemm2<<<gb, 256, 0, stream>>>(hmid, W2, h2, N);
    k_att2<<<nb4, 256, 0, stream>>>(h2, as2, ad2, a2s, a2d, N);
    k_gat2<<<nb4, 256, 0, stream>>>(row_start, csr_src, h2, a2s, a2d, b2, (float*)d_out, N);
}

// Round 6
// 406.501 us; speedup vs baseline: 1.0025x; 1.0025x over previous
//
#include <hip/hip_runtime.h>
#include <cstdint>

// ---------------- CSR build ----------------

__global__ __launch_bounds__(256) void k_hist(const int* __restrict__ ei,
        int E, int E2, int* __restrict__ deg) {
    int e = blockIdx.x * 256 + threadIdx.x;
    if (e >= E2) return;
    int dst = (e < E) ? ei[E + e] : (e - E);
    atomicAdd(&deg[dst], 1);
}

__global__ __launch_bounds__(1024) void k_scan(const int* __restrict__ deg,
        int* __restrict__ row_start, int N) {
    __shared__ int buf[1024];
    int t = threadIdx.x;
    int chunk = (N + 1023) >> 10;
    int lo = t * chunk, hi = min(lo + chunk, N);
    int s = 0;
    for (int i = lo; i < hi; ++i) s += deg[i];
    buf[t] = s;
    __syncthreads();
    for (int off = 1; off < 1024; off <<= 1) {
        int v = (t >= off) ? buf[t - off] : 0;
        __syncthreads();
        buf[t] += v;
        __syncthreads();
    }
    int run = buf[t] - s;  // exclusive prefix
    for (int i = lo; i < hi; ++i) { row_start[i] = run; run += deg[i]; }
    if (t == 1023) row_start[N] = buf[1023];
}

__global__ __launch_bounds__(256) void k_scatter(const int* __restrict__ ei,
        int E, int E2, const int* __restrict__ row_start, int* __restrict__ cursor,
        int* __restrict__ csr_src, int* __restrict__ csr_dst) {
    int e = blockIdx.x * 256 + threadIdx.x;
    if (e >= E2) return;
    int src, dst;
    if (e < E) { src = ei[e]; dst = ei[E + e]; }
    else       { src = e - E; dst = src; }
    int pos = row_start[dst] + atomicAdd(&cursor[dst], 1);
    csr_src[pos] = src;
    csr_dst[pos] = dst;
}

// ---------------- GEMM1: [N,512] @ [512,64] -> h1 [N,64] ----------------
// 64x64 tile, BK=16, register-prefetch pipelined: next tile's global loads
// issue before the FMA loop so HBM latency hides under compute.

__global__ __launch_bounds__(256) void k_gemm1(const float* __restrict__ x,
        const float* __restrict__ W, float* __restrict__ h1, int N) {
    __shared__ float xs[64][17];
    __shared__ float ws[16][64];
    int t = threadIdx.x;
    int row0 = blockIdx.x * 64;
    int c0 = (t & 15) * 4;
    int r0 = (t >> 4) * 4;
    int lr = t >> 2, lf = t & 3;           // x staging: row lr, float4 slot lf
    int wr = t >> 4, wc = (t & 15) * 4;    // W staging
    int xrow = min(row0 + lr, N - 1);      // clamp: garbage rows masked on store
    const float* xbase = x + (size_t)xrow * 512 + lf * 4;
    float4 xv = *(const float4*)(xbase);
    float4 wv = *(const float4*)(W + (size_t)wr * 64 + wc);
    float4 acc[4] = {};
    for (int k0 = 0; k0 < 512; k0 += 16) {
        __syncthreads();   // previous iter's readers done
        xs[lr][lf * 4 + 0] = xv.x; xs[lr][lf * 4 + 1] = xv.y;
        xs[lr][lf * 4 + 2] = xv.z; xs[lr][lf * 4 + 3] = xv.w;
        *(float4*)&ws[wr][wc] = wv;
        __syncthreads();
        if (k0 + 16 < 512) {   // prefetch next tile; latency overlaps FMAs below
            xv = *(const float4*)(xbase + k0 + 16);
            wv = *(const float4*)(W + (size_t)(k0 + 16 + wr) * 64 + wc);
        }
        #pragma unroll
        for (int kk = 0; kk < 16; ++kk) {
            float4 w4 = *(const float4*)&ws[kk][c0];
            #pragma unroll
            for (int i = 0; i < 4; ++i) {
                float a = xs[r0 + i][kk];
                acc[i].x += a * w4.x; acc[i].y += a * w4.y;
                acc[i].z += a * w4.z; acc[i].w += a * w4.w;
            }
        }
    }
    #pragma unroll
    for (int i = 0; i < 4; ++i) {
        int row = row0 + r0 + i;
        if (row < N) *(float4*)(h1 + (size_t)row * 64 + c0) = acc[i];
    }
}

// ---------------- GEMM2: [N,64] @ [64,128] -> h2 [N,128] ----------------

__global__ __launch_bounds__(256) void k_gemm2(const float* __restrict__ hin,
        const float* __restrict__ W, float* __restrict__ h2, int N) {
    __shared__ float xs[64][65];
    __shared__ float ws[64][128];
    int t = threadIdx.x;
    int row0 = blockIdx.x * 64;
    #pragma unroll
    for (int u = 0; u < 4; ++u) {
        int idx = t + u * 256;       // float4 index into 64x64 tile
        int r = idx >> 4, f = idx & 15;
        int grow = row0 + r;
        float4 v = make_float4(0.f, 0.f, 0.f, 0.f);
        if (grow < N) v = *(const float4*)(hin + (size_t)grow * 64 + f * 4);
        xs[r][f * 4 + 0] = v.x; xs[r][f * 4 + 1] = v.y;
        xs[r][f * 4 + 2] = v.z; xs[r][f * 4 + 3] = v.w;
    }
    #pragma unroll
    for (int u = 0; u < 8; ++u) {
        int idx = t + u * 256;
        int kr = idx >> 5, c4 = (idx & 31) * 4;
        *(float4*)&ws[kr][c4] = *(const float4*)(W + (size_t)kr * 128 + c4);
    }
    __syncthreads();
    int c0 = (t & 15) * 8;
    int r0 = (t >> 4) * 4;
    float4 acc[4][2] = {};
    #pragma unroll 8
    for (int kk = 0; kk < 64; ++kk) {
        float4 w0 = *(const float4*)&ws[kk][c0];
        float4 w1 = *(const float4*)&ws[kk][c0 + 4];
        #pragma unroll
        for (int i = 0; i < 4; ++i) {
            float a = xs[r0 + i][kk];
            acc[i][0].x += a * w0.x; acc[i][0].y += a * w0.y;
            acc[i][0].z += a * w0.z; acc[i][0].w += a * w0.w;
            acc[i][1].x += a * w1.x; acc[i][1].y += a * w1.y;
            acc[i][1].z += a * w1.z; acc[i][1].w += a * w1.w;
        }
    }
    #pragma unroll
    for (int i = 0; i < 4; ++i) {
        int row = row0 + r0 + i;
        if (row < N) {
            *(float4*)(h2 + (size_t)row * 128 + c0) = acc[i][0];
            *(float4*)(h2 + (size_t)row * 128 + c0 + 4) = acc[i][1];
        }
    }
}

// ---------------- attention coefficients ----------------

__global__ __launch_bounds__(256) void k_att1(const float* __restrict__ h1,
        const float* __restrict__ att_src, const float* __restrict__ att_dst,
        float* __restrict__ a_s, float* __restrict__ a_d, int NH) {
    int i = blockIdx.x * 256 + threadIdx.x;
    if (i >= NH) return;
    int h = i & 7;
    const float* hp = h1 + (size_t)i * 8;
    const float* sp = att_src + h * 8;
    const float* dp = att_dst + h * 8;
    float s = 0.f, d = 0.f;
    #pragma unroll
    for (int c = 0; c < 8; ++c) { float v = hp[c]; s += v * sp[c]; d += v * dp[c]; }
    a_s[i] = s; a_d[i] = d;
}

__global__ __launch_bounds__(256) void k_att2(const float* __restrict__ h2,
        const float* __restrict__ att_src, const float* __restrict__ att_dst,
        float* __restrict__ a_s, float* __restrict__ a_d, int N) {
    int node = blockIdx.x * 4 + (threadIdx.x >> 6);
    int lane = threadIdx.x & 63;
    if (node >= N) return;
    const float* hp = h2 + (size_t)node * 128;
    float v0 = hp[lane], v1 = hp[lane + 64];
    float s = v0 * att_src[lane] + v1 * att_src[lane + 64];
    float d = v0 * att_dst[lane] + v1 * att_dst[lane + 64];
    #pragma unroll
    for (int off = 32; off >= 1; off >>= 1) {
        s += __shfl_xor(s, off, 64);
        d += __shfl_xor(d, off, 64);
    }
    if (lane == 0) { a_s[node] = s; a_d[node] = d; }
}

// ---------------- edge weights (exp once per edge, not per lane) ----------------

__global__ __launch_bounds__(256) void k_ew1(const int* __restrict__ csr_src,
        const int* __restrict__ csr_dst, const float* __restrict__ a_s,
        const float* __restrict__ a_d, float* __restrict__ w1, int E2) {
    int p = blockIdx.x * 256 + threadIdx.x;
    if (p >= E2) return;
    int s = csr_src[p], d = csr_dst[p];
    float4 s0 = *(const float4*)(a_s + (size_t)s * 8);
    float4 s1 = *(const float4*)(a_s + (size_t)s * 8 + 4);
    float4 d0 = *(const float4*)(a_d + (size_t)d * 8);
    float4 d1 = *(const float4*)(a_d + (size_t)d * 8 + 4);
    float al[8] = { s0.x + d0.x, s0.y + d0.y, s0.z + d0.z, s0.w + d0.w,
                    s1.x + d1.x, s1.y + d1.y, s1.z + d1.z, s1.w + d1.w };
    float o[8];
    #pragma unroll
    for (int h = 0; h < 8; ++h) {
        float a = al[h];
        a = a > 0.f ? a : 0.2f * a;
        o[h] = __expf(a);
    }
    *(float4*)(w1 + (size_t)p * 8)     = make_float4(o[0], o[1], o[2], o[3]);
    *(float4*)(w1 + (size_t)p * 8 + 4) = make_float4(o[4], o[5], o[6], o[7]);
}

__global__ __launch_bounds__(256) void k_ew2(const int* __restrict__ csr_src,
        const int* __restrict__ csr_dst, const float* __restrict__ a_s,
        const float* __restrict__ a_d, float* __restrict__ w2, int E2) {
    int p = blockIdx.x * 256 + threadIdx.x;
    if (p >= E2) return;
    float a = a_s[csr_src[p]] + a_d[csr_dst[p]];
    a = a > 0.f ? a : 0.2f * a;
    w2[p] = __expf(a);
}

// ---------------- GAT aggregation, layer 1 (H=8, C=8) + bias + ELU ----------------
// one 64-lane wave per dst node; lane = output channel; h = lane>>3.

__global__ __launch_bounds__(256) void k_gat1(
        const int* __restrict__ row_start, const int* __restrict__ csr_src,
        const float* __restrict__ w1, const float* __restrict__ h1,
        const float* __restrict__ bias, float* __restrict__ outp, int N) {
    int node = blockIdx.x * 4 + (threadIdx.x >> 6);
    int lane = threadIdx.x & 63;
    if (node >= N) return;
    int h = lane >> 3;
    int start = row_start[node], end = row_start[node + 1];

    // denominator: lane-parallel sum of precomputed weights (coalesced)
    float dh[8] = {0.f,0.f,0.f,0.f,0.f,0.f,0.f,0.f};
    for (int idx = start + lane; idx < end; idx += 64) {
        float4 w0 = *(const float4*)(w1 + (size_t)idx * 8);
        float4 w4 = *(const float4*)(w1 + (size_t)idx * 8 + 4);
        dh[0] += w0.x; dh[1] += w0.y; dh[2] += w0.z; dh[3] += w0.w;
        dh[4] += w4.x; dh[5] += w4.y; dh[6] += w4.z; dh[7] += w4.w;
    }
    #pragma unroll
    for (int hh = 0; hh < 8; ++hh) {
        #pragma unroll
        for (int off = 32; off >= 1; off >>= 1) dh[hh] += __shfl_xor(dh[hh], off, 64);
    }
    float den = dh[0];
    #pragma unroll
    for (int hh = 1; hh < 8; ++hh) den = (h == hh) ? dh[hh] : den;
    float inv = 1.f / (den + 1e-16f);

    // weighted accumulate: w lines are L1-hot from the denominator pass
    float acc = 0.f;
    for (int base = start; base < end; base += 64) {
        int idx = base + lane;
        int sv = (idx < end) ? csr_src[idx] : 0;
        int cnt = min(64, end - base);
        if (cnt == 64) {
            #pragma unroll 4
            for (int j = 0; j < 64; ++j) {
                int s = __shfl(sv, j, 64);
                float w = w1[(size_t)(base + j) * 8 + h];
                acc += h1[(size_t)s * 64 + lane] * w;
            }
        } else {
            for (int j = 0; j < cnt; ++j) {
                int s = __shfl(sv, j, 64);
                float w = w1[(size_t)(base + j) * 8 + h];
                acc += h1[(size_t)s * 64 + lane] * w;
            }
        }
    }
    float v = acc * inv + bias[lane];
    outp[(size_t)node * 64 + lane] = v > 0.f ? v : __expf(v) - 1.f;  // ELU
}

// ---------------- GAT aggregation, layer 2 (H=1, C=128) + bias ----------------

__global__ __launch_bounds__(256) void k_gat2(
        const int* __restrict__ row_start, const int* __restrict__ csr_src,
        const float* __restrict__ w2, const float* __restrict__ h2,
        const float* __restrict__ bias, float* __restrict__ outp, int N) {
    int node = blockIdx.x * 4 + (threadIdx.x >> 6);
    int lane = threadIdx.x & 63;
    if (node >= N) return;
    int start = row_start[node], end = row_start[node + 1];

    float dsum = 0.f;
    for (int idx = start + lane; idx < end; idx += 64) dsum += w2[idx];
    #pragma unroll
    for (int off = 32; off >= 1; off >>= 1) dsum += __shfl_xor(dsum, off, 64);
    float inv = 1.f / (dsum + 1e-16f);

    float acc0 = 0.f, acc1 = 0.f;
    for (int base = start; base < end; base += 64) {
        int idx = base + lane;
        int sv = (idx < end) ? csr_src[idx] : 0;
        float wv = (idx < end) ? w2[idx] : 0.f;
        int cnt = min(64, end - base);
        if (cnt == 64) {
            #pragma unroll 4
            for (int j = 0; j < 64; ++j) {
                int s = __shfl(sv, j, 64);
                float w = __shfl(wv, j, 64);
                const float* hp = h2 + (size_t)s * 128;
                acc0 += hp[lane] * w;
                acc1 += hp[lane + 64] * w;
            }
        } else {
            for (int j = 0; j < cnt; ++j) {
                int s = __shfl(sv, j, 64);
                float w = __shfl(wv, j, 64);
                const float* hp = h2 + (size_t)s * 128;
                acc0 += hp[lane] * w;
                acc1 += hp[lane + 64] * w;
            }
        }
    }
    outp[(size_t)node * 128 + lane]      = acc0 * inv + bias[lane];
    outp[(size_t)node * 128 + lane + 64] = acc1 * inv + bias[lane + 64];
}

// ---------------- launcher ----------------

extern "C" void kernel_launch(void* const* d_in, const int* in_sizes, int n_in,
                              void* d_out, int out_size, void* d_ws, size_t ws_size,
                              hipStream_t stream) {
    const float* x   = (const float*)d_in[0];
    const int*   ei  = (const int*)d_in[1];     // integer inputs arrive as int32
    const float* W1  = (const float*)d_in[2];
    const float* as1 = (const float*)d_in[3];
    const float* ad1 = (const float*)d_in[4];
    const float* b1  = (const float*)d_in[5];
    const float* W2  = (const float*)d_in[6];
    const float* as2 = (const float*)d_in[7];
    const float* ad2 = (const float*)d_in[8];
    const float* b2  = (const float*)d_in[9];
    int N  = in_sizes[0] / 512;
    int E  = in_sizes[1] / 2;
    int E2 = E + N;

    char* wsp = (char*)d_ws;
    size_t off = 0;
    auto alloc = [&](size_t bytes) {
        char* p = wsp + off;
        off = (off + bytes + 255) & ~(size_t)255;
        return p;
    };
    float* h1   = (float*)alloc((size_t)N * 64 * 4);
    float* hmid = (float*)alloc((size_t)N * 64 * 4);
    float* h2   = (float*)alloc((size_t)N * 128 * 4);
    float* a1s  = (float*)alloc((size_t)N * 8 * 4);
    float* a1d  = (float*)alloc((size_t)N * 8 * 4);
    float* a2s  = (float*)alloc((size_t)N * 4);
    float* a2d  = (float*)alloc((size_t)N * 4);
    int* deg    = (int*)alloc((size_t)2 * N * 4);  // deg | cursor
    int* cursor = deg + N;
    int* row_start = (int*)alloc((size_t)(N + 1) * 4);
    int* csr_src   = (int*)alloc((size_t)E2 * 4);
    int* csr_dst   = (int*)alloc((size_t)E2 * 4);
    float* w1      = (float*)alloc((size_t)E2 * 8 * 4);
    float* w2      = (float*)alloc((size_t)E2 * 4);
    (void)ws_size; (void)n_in; (void)out_size;

    hipMemsetAsync(deg, 0, (size_t)2 * N * 4, stream);
    int eb = (E2 + 255) / 256;
    k_hist<<<eb, 256, 0, stream>>>(ei, E, E2, deg);
    k_scan<<<1, 1024, 0, stream>>>(deg, row_start, N);
    k_scatter<<<eb, 256, 0, stream>>>(ei, E, E2, row_start, cursor, csr_src, csr_dst);

    int gb = (N + 63) / 64;
    int nb4 = (N + 3) / 4;
    k_gemm1<<<gb, 256, 0, stream>>>(x, W1, h1, N);
    k_att1<<<(N * 8 + 255) / 256, 256, 0, stream>>>(h1, as1, ad1, a1s, a1d, N * 8);
    k_ew1<<<eb, 256, 0, stream>>>(csr_src, csr_dst, a1s, a1d, w1, E2);
    k_gat1<<<nb4, 256, 0, stream>>>(row_start, csr_src, w1, h1, b1, hmid, N);
    k_gemm2<<<gb, 256, 0, stream>>>(hmid, W2, h2, N);
    k_att2<<<nb4, 256, 0, stream>>>(h2, as2, ad2, a2s, a2d, N);
    k_ew2<<<eb, 256, 0, stream>>>(csr_src, csr_dst, a2s, a2d, w2, E2);
    k_gat2<<<nb4, 256, 0, stream>>>(row_start, csr_src, w2, h2, b2, (float*)d_out, N);
}

// Round 7
// 328.440 us; speedup vs baseline: 1.2408x; 1.2377x over previous
//
#include <hip/hip_runtime.h>
#include <cstdint>

// ---------------- CSR build ----------------

__global__ __launch_bounds__(256) void k_hist(const int* __restrict__ ei,
        int E, int E2, int* __restrict__ deg) {
    int e = blockIdx.x * 256 + threadIdx.x;
    if (e >= E2) return;
    int dst = (e < E) ? ei[E + e] : (e - E);
    atomicAdd(&deg[dst], 1);
}

// 3-phase multi-block exclusive scan of deg[0..N) -> row_start[0..N]
// phase A: per-block (2048 elems) partial sums
__global__ __launch_bounds__(256) void k_scanA(const int* __restrict__ deg,
        int* __restrict__ partials, int N) {
    int t = threadIdx.x;
    int base = blockIdx.x * 2048 + t * 8;
    int s = 0;
    #pragma unroll
    for (int j = 0; j < 8; ++j) { int i = base + j; if (i < N) s += deg[i]; }
    #pragma unroll
    for (int off = 32; off >= 1; off >>= 1) s += __shfl_xor(s, off, 64);
    __shared__ int ws[4];
    if ((t & 63) == 0) ws[t >> 6] = s;
    __syncthreads();
    if (t == 0) partials[blockIdx.x] = ws[0] + ws[1] + ws[2] + ws[3];
}

// phase B: one wave scans the partials (exclusive, in place) + writes total
__global__ __launch_bounds__(64) void k_scanB(int* __restrict__ partials,
        int nb, int* __restrict__ row_start, int N) {
    int lane = threadIdx.x;
    int run = 0;
    for (int b0 = 0; b0 < nb; b0 += 64) {
        int v = (b0 + lane < nb) ? partials[b0 + lane] : 0;
        int s = v;
        #pragma unroll
        for (int d = 1; d < 64; d <<= 1) {
            int u = __shfl_up(s, d, 64);
            if (lane >= d) s += u;
        }
        if (b0 + lane < nb) partials[b0 + lane] = run + s - v;  // exclusive
        run += __shfl(s, 63, 64);
    }
    if (lane == 0) row_start[N] = run;
}

// phase C: block-local exclusive scan + block offset -> row_start
__global__ __launch_bounds__(256) void k_scanC(const int* __restrict__ deg,
        const int* __restrict__ partials, int* __restrict__ row_start, int N) {
    int t = threadIdx.x;
    int base = blockIdx.x * 2048 + t * 8;
    int v[8], s = 0;
    #pragma unroll
    for (int j = 0; j < 8; ++j) { int i = base + j; v[j] = (i < N) ? deg[i] : 0; s += v[j]; }
    int lane = t & 63, w = t >> 6;
    int incl = s;
    #pragma unroll
    for (int d = 1; d < 64; d <<= 1) {
        int u = __shfl_up(incl, d, 64);
        if (lane >= d) incl += u;
    }
    __shared__ int wsum[4];
    if (lane == 63) wsum[w] = incl;
    __syncthreads();
    int woff = 0;
    #pragma unroll
    for (int i = 0; i < 4; ++i) if (i < w) woff += wsum[i];
    int run = partials[blockIdx.x] + woff + incl - s;  // thread's exclusive prefix
    #pragma unroll
    for (int j = 0; j < 8; ++j) {
        int i = base + j;
        if (i < N) row_start[i] = run;
        run += v[j];
    }
}

__global__ __launch_bounds__(256) void k_scatter(const int* __restrict__ ei,
        int E, int E2, const int* __restrict__ row_start, int* __restrict__ cursor,
        int* __restrict__ csr_src) {
    int e = blockIdx.x * 256 + threadIdx.x;
    if (e >= E2) return;
    int src, dst;
    if (e < E) { src = ei[e]; dst = ei[E + e]; }
    else       { src = e - E; dst = src; }
    int pos = row_start[dst] + atomicAdd(&cursor[dst], 1);
    csr_src[pos] = src;
}

// ---------------- GEMM1: [N,512] @ [512,64] -> h1 [N,64] ----------------
// 64x64 tile, BK=16, register-prefetch pipelined.

__global__ __launch_bounds__(256) void k_gemm1(const float* __restrict__ x,
        const float* __restrict__ W, float* __restrict__ h1, int N) {
    __shared__ float xs[64][17];
    __shared__ float ws[16][64];
    int t = threadIdx.x;
    int row0 = blockIdx.x * 64;
    int c0 = (t & 15) * 4;
    int r0 = (t >> 4) * 4;
    int lr = t >> 2, lf = t & 3;
    int wr = t >> 4, wc = (t & 15) * 4;
    int xrow = min(row0 + lr, N - 1);
    const float* xbase = x + (size_t)xrow * 512 + lf * 4;
    float4 xv = *(const float4*)(xbase);
    float4 wv = *(const float4*)(W + (size_t)wr * 64 + wc);
    float4 acc[4] = {};
    for (int k0 = 0; k0 < 512; k0 += 16) {
        __syncthreads();
        xs[lr][lf * 4 + 0] = xv.x; xs[lr][lf * 4 + 1] = xv.y;
        xs[lr][lf * 4 + 2] = xv.z; xs[lr][lf * 4 + 3] = xv.w;
        *(float4*)&ws[wr][wc] = wv;
        __syncthreads();
        if (k0 + 16 < 512) {
            xv = *(const float4*)(xbase + k0 + 16);
            wv = *(const float4*)(W + (size_t)(k0 + 16 + wr) * 64 + wc);
        }
        #pragma unroll
        for (int kk = 0; kk < 16; ++kk) {
            float4 w4 = *(const float4*)&ws[kk][c0];
            #pragma unroll
            for (int i = 0; i < 4; ++i) {
                float a = xs[r0 + i][kk];
                acc[i].x += a * w4.x; acc[i].y += a * w4.y;
                acc[i].z += a * w4.z; acc[i].w += a * w4.w;
            }
        }
    }
    #pragma unroll
    for (int i = 0; i < 4; ++i) {
        int row = row0 + r0 + i;
        if (row < N) *(float4*)(h1 + (size_t)row * 64 + c0) = acc[i];
    }
}

// ---------------- GEMM2: [N,64] @ [64,128] -> h2 [N,128] ----------------

__global__ __launch_bounds__(256) void k_gemm2(const float* __restrict__ hin,
        const float* __restrict__ W, float* __restrict__ h2, int N) {
    __shared__ float xs[64][65];
    __shared__ float ws[64][128];
    int t = threadIdx.x;
    int row0 = blockIdx.x * 64;
    #pragma unroll
    for (int u = 0; u < 4; ++u) {
        int idx = t + u * 256;
        int r = idx >> 4, f = idx & 15;
        int grow = row0 + r;
        float4 v = make_float4(0.f, 0.f, 0.f, 0.f);
        if (grow < N) v = *(const float4*)(hin + (size_t)grow * 64 + f * 4);
        xs[r][f * 4 + 0] = v.x; xs[r][f * 4 + 1] = v.y;
        xs[r][f * 4 + 2] = v.z; xs[r][f * 4 + 3] = v.w;
    }
    #pragma unroll
    for (int u = 0; u < 8; ++u) {
        int idx = t + u * 256;
        int kr = idx >> 5, c4 = (idx & 31) * 4;
        *(float4*)&ws[kr][c4] = *(const float4*)(W + (size_t)kr * 128 + c4);
    }
    __syncthreads();
    int c0 = (t & 15) * 8;
    int r0 = (t >> 4) * 4;
    float4 acc[4][2] = {};
    #pragma unroll 8
    for (int kk = 0; kk < 64; ++kk) {
        float4 w0 = *(const float4*)&ws[kk][c0];
        float4 w1 = *(const float4*)&ws[kk][c0 + 4];
        #pragma unroll
        for (int i = 0; i < 4; ++i) {
            float a = xs[r0 + i][kk];
            acc[i][0].x += a * w0.x; acc[i][0].y += a * w0.y;
            acc[i][0].z += a * w0.z; acc[i][0].w += a * w0.w;
            acc[i][1].x += a * w1.x; acc[i][1].y += a * w1.y;
            acc[i][1].z += a * w1.z; acc[i][1].w += a * w1.w;
        }
    }
    #pragma unroll
    for (int i = 0; i < 4; ++i) {
        int row = row0 + r0 + i;
        if (row < N) {
            *(float4*)(h2 + (size_t)row * 128 + c0) = acc[i][0];
            *(float4*)(h2 + (size_t)row * 128 + c0 + 4) = acc[i][1];
        }
    }
}

// ---------------- attention coefficients ----------------

__global__ __launch_bounds__(256) void k_att1(const float* __restrict__ h1,
        const float* __restrict__ att_src, const float* __restrict__ att_dst,
        float* __restrict__ a_s, float* __restrict__ a_d, int NH) {
    int i = blockIdx.x * 256 + threadIdx.x;
    if (i >= NH) return;
    int h = i & 7;
    const float* hp = h1 + (size_t)i * 8;
    const float* sp = att_src + h * 8;
    const float* dp = att_dst + h * 8;
    float s = 0.f, d = 0.f;
    #pragma unroll
    for (int c = 0; c < 8; ++c) { float v = hp[c]; s += v * sp[c]; d += v * dp[c]; }
    a_s[i] = s; a_d[i] = d;
}

__global__ __launch_bounds__(256) void k_att2(const float* __restrict__ h2,
        const float* __restrict__ att_src, const float* __restrict__ att_dst,
        float* __restrict__ a_s, float* __restrict__ a_d, int N) {
    int node = blockIdx.x * 4 + (threadIdx.x >> 6);
    int lane = threadIdx.x & 63;
    if (node >= N) return;
    const float* hp = h2 + (size_t)node * 128;
    float v0 = hp[lane], v1 = hp[lane + 64];
    float s = v0 * att_src[lane] + v1 * att_src[lane + 64];
    float d = v0 * att_dst[lane] + v1 * att_dst[lane + 64];
    #pragma unroll
    for (int off = 32; off >= 1; off >>= 1) {
        s += __shfl_xor(s, off, 64);
        d += __shfl_xor(d, off, 64);
    }
    if (lane == 0) { a_s[node] = s; a_d[node] = d; }
}

// ---------------- GAT aggregation, layer 1 (H=8, C=8) + bias + ELU ----------------
// one 64-lane wave per dst node. Pass 1 computes per-edge weights (exp once
// per edge, lane-parallel), stores them, and accumulates the denominator.
// Pass 2 does the edge-serial weighted gather with L1/L2-hot weights.

__global__ __launch_bounds__(256) void k_gat1(
        const int* __restrict__ row_start, const int* __restrict__ csr_src,
        float* __restrict__ w1, const float* __restrict__ h1,
        const float* __restrict__ a_src, const float* __restrict__ a_dst,
        const float* __restrict__ bias, float* __restrict__ outp, int N) {
    int node = blockIdx.x * 4 + (threadIdx.x >> 6);
    int lane = threadIdx.x & 63;
    if (node >= N) return;
    int h = lane >> 3;
    int start = row_start[node], end = row_start[node + 1];

    float ad8[8];
    #pragma unroll
    for (int hh = 0; hh < 8; ++hh) ad8[hh] = a_dst[(size_t)node * 8 + hh];

    // pass 1: weights + denominator
    float dh[8] = {0.f,0.f,0.f,0.f,0.f,0.f,0.f,0.f};
    for (int idx = start + lane; idx < end; idx += 64) {
        int s = csr_src[idx];
        float4 s0 = *(const float4*)(a_src + (size_t)s * 8);
        float4 s1 = *(const float4*)(a_src + (size_t)s * 8 + 4);
        float al[8] = { s0.x + ad8[0], s0.y + ad8[1], s0.z + ad8[2], s0.w + ad8[3],
                        s1.x + ad8[4], s1.y + ad8[5], s1.z + ad8[6], s1.w + ad8[7] };
        float o[8];
        #pragma unroll
        for (int hh = 0; hh < 8; ++hh) {
            float a = al[hh];
            a = a > 0.f ? a : 0.2f * a;
            o[hh] = __expf(a);
            dh[hh] += o[hh];
        }
        *(float4*)(w1 + (size_t)idx * 8)     = make_float4(o[0], o[1], o[2], o[3]);
        *(float4*)(w1 + (size_t)idx * 8 + 4) = make_float4(o[4], o[5], o[6], o[7]);
    }
    #pragma unroll
    for (int hh = 0; hh < 8; ++hh) {
        #pragma unroll
        for (int off = 32; off >= 1; off >>= 1) dh[hh] += __shfl_xor(dh[hh], off, 64);
    }
    float den = dh[0];
    #pragma unroll
    for (int hh = 1; hh < 8; ++hh) den = (h == hh) ? dh[hh] : den;
    float inv = 1.f / (den + 1e-16f);

    // pass 2: weighted accumulate (w lines L1-hot from pass 1)
    float acc = 0.f;
    for (int base = start; base < end; base += 64) {
        int idx = base + lane;
        int sv = (idx < end) ? csr_src[idx] : 0;
        int cnt = min(64, end - base);
        if (cnt == 64) {
            #pragma unroll 4
            for (int j = 0; j < 64; ++j) {
                int s = __shfl(sv, j, 64);
                float w = w1[(size_t)(base + j) * 8 + h];
                acc += h1[(size_t)s * 64 + lane] * w;
            }
        } else {
            for (int j = 0; j < cnt; ++j) {
                int s = __shfl(sv, j, 64);
                float w = w1[(size_t)(base + j) * 8 + h];
                acc += h1[(size_t)s * 64 + lane] * w;
            }
        }
    }
    float v = acc * inv + bias[lane];
    outp[(size_t)node * 64 + lane] = v > 0.f ? v : __expf(v) - 1.f;  // ELU
}

// ---------------- GAT aggregation, layer 2 (H=1, C=128) + bias ----------------

__global__ __launch_bounds__(256) void k_gat2(
        const int* __restrict__ row_start, const int* __restrict__ csr_src,
        float* __restrict__ w2, const float* __restrict__ h2,
        const float* __restrict__ a_src, const float* __restrict__ a_dst,
        const float* __restrict__ bias, float* __restrict__ outp, int N) {
    int node = blockIdx.x * 4 + (threadIdx.x >> 6);
    int lane = threadIdx.x & 63;
    if (node >= N) return;
    int start = row_start[node], end = row_start[node + 1];
    float adst = a_dst[node];

    // pass 1: weights + denominator
    float dsum = 0.f;
    for (int idx = start + lane; idx < end; idx += 64) {
        float a = a_src[csr_src[idx]] + adst;
        a = a > 0.f ? a : 0.2f * a;
        float w = __expf(a);
        w2[idx] = w;
        dsum += w;
    }
    #pragma unroll
    for (int off = 32; off >= 1; off >>= 1) dsum += __shfl_xor(dsum, off, 64);
    float inv = 1.f / (dsum + 1e-16f);

    // pass 2: weighted accumulate
    float acc0 = 0.f, acc1 = 0.f;
    for (int base = start; base < end; base += 64) {
        int idx = base + lane;
        int sv = (idx < end) ? csr_src[idx] : 0;
        float wv = (idx < end) ? w2[idx] : 0.f;
        int cnt = min(64, end - base);
        if (cnt == 64) {
            #pragma unroll 4
            for (int j = 0; j < 64; ++j) {
                int s = __shfl(sv, j, 64);
                float w = __shfl(wv, j, 64);
                const float* hp = h2 + (size_t)s * 128;
                acc0 += hp[lane] * w;
                acc1 += hp[lane + 64] * w;
            }
        } else {
            for (int j = 0; j < cnt; ++j) {
                int s = __shfl(sv, j, 64);
                float w = __shfl(wv, j, 64);
                const float* hp = h2 + (size_t)s * 128;
                acc0 += hp[lane] * w;
                acc1 += hp[lane + 64] * w;
            }
        }
    }
    outp[(size_t)node * 128 + lane]      = acc0 * inv + bias[lane];
    outp[(size_t)node * 128 + lane + 64] = acc1 * inv + bias[lane + 64];
}

// ---------------- launcher ----------------

extern "C" void kernel_launch(void* const* d_in, const int* in_sizes, int n_in,
                              void* d_out, int out_size, void* d_ws, size_t ws_size,
                              hipStream_t stream) {
    const float* x   = (const float*)d_in[0];
    const int*   ei  = (const int*)d_in[1];     // integer inputs arrive as int32
    const float* W1  = (const float*)d_in[2];
    const float* as1 = (const float*)d_in[3];
    const float* ad1 = (const float*)d_in[4];
    const float* b1  = (const float*)d_in[5];
    const float* W2  = (const float*)d_in[6];
    const float* as2 = (const float*)d_in[7];
    const float* ad2 = (const float*)d_in[8];
    const float* b2  = (const float*)d_in[9];
    int N  = in_sizes[0] / 512;
    int E  = in_sizes[1] / 2;
    int E2 = E + N;

    char* wsp = (char*)d_ws;
    size_t off = 0;
    auto alloc = [&](size_t bytes) {
        char* p = wsp + off;
        off = (off + bytes + 255) & ~(size_t)255;
        return p;
    };
    float* h1   = (float*)alloc((size_t)N * 64 * 4);
    float* hmid = (float*)alloc((size_t)N * 64 * 4);
    float* h2   = (float*)alloc((size_t)N * 128 * 4);
    float* a1s  = (float*)alloc((size_t)N * 8 * 4);
    float* a1d  = (float*)alloc((size_t)N * 8 * 4);
    float* a2s  = (float*)alloc((size_t)N * 4);
    float* a2d  = (float*)alloc((size_t)N * 4);
    int* deg    = (int*)alloc((size_t)2 * N * 4);  // deg | cursor
    int* cursor = deg + N;
    int* row_start = (int*)alloc((size_t)(N + 1) * 4);
    int* csr_src   = (int*)alloc((size_t)E2 * 4);
    float* w1      = (float*)alloc((size_t)E2 * 8 * 4);
    float* w2      = (float*)alloc((size_t)E2 * 4);
    int nbscan = (N + 2047) / 2048;
    int* partials  = (int*)alloc((size_t)nbscan * 4);
    (void)ws_size; (void)n_in; (void)out_size;

    hipMemsetAsync(deg, 0, (size_t)2 * N * 4, stream);
    int eb = (E2 + 255) / 256;
    k_hist<<<eb, 256, 0, stream>>>(ei, E, E2, deg);
    k_scanA<<<nbscan, 256, 0, stream>>>(deg, partials, N);
    k_scanB<<<1, 64, 0, stream>>>(partials, nbscan, row_start, N);
    k_scanC<<<nbscan, 256, 0, stream>>>(deg, partials, row_start, N);
    k_scatter<<<eb, 256, 0, stream>>>(ei, E, E2, row_start, cursor, csr_src);

    int gb = (N + 63) / 64;
    int nb4 = (N + 3) / 4;
    k_gemm1<<<gb, 256, 0, stream>>>(x, W1, h1, N);
    k_att1<<<(N * 8 + 255) / 256, 256, 0, stream>>>(h1, as1, ad1, a1s, a1d, N * 8);
    k_gat1<<<nb4, 256, 0, stream>>>(row_start, csr_src, w1, h1, a1s, a1d, b1, hmid, N);
    k_gemm2<<<gb, 256, 0, stream>>>(hmid, W2, h2, N);
    k_att2<<<nb4, 256, 0, stream>>>(h2, as2, ad2, a2s, a2d, N);
    k_gat2<<<nb4, 256, 0, stream>>>(row_start, csr_src, w2, h2, a2s, a2d, b2, (float*)d_out, N);
}

// Round 8
// 318.485 us; speedup vs baseline: 1.2796x; 1.0313x over previous
//
#include <hip/hip_runtime.h>
#include <cstdint>

// ---------------- CSR build ----------------

__global__ __launch_bounds__(256) void k_hist(const int* __restrict__ ei,
        int E, int E2, int* __restrict__ deg) {
    int e = blockIdx.x * 256 + threadIdx.x;
    if (e >= E2) return;
    int dst = (e < E) ? ei[E + e] : (e - E);
    atomicAdd(&deg[dst], 1);
}

// 3-phase multi-block exclusive scan of deg[0..N) -> row_start[0..N]
__global__ __launch_bounds__(256) void k_scanA(const int* __restrict__ deg,
        int* __restrict__ partials, int N) {
    int t = threadIdx.x;
    int base = blockIdx.x * 2048 + t * 8;
    int s = 0;
    #pragma unroll
    for (int j = 0; j < 8; ++j) { int i = base + j; if (i < N) s += deg[i]; }
    #pragma unroll
    for (int off = 32; off >= 1; off >>= 1) s += __shfl_xor(s, off, 64);
    __shared__ int ws[4];
    if ((t & 63) == 0) ws[t >> 6] = s;
    __syncthreads();
    if (t == 0) partials[blockIdx.x] = ws[0] + ws[1] + ws[2] + ws[3];
}

__global__ __launch_bounds__(64) void k_scanB(int* __restrict__ partials,
        int nb, int* __restrict__ row_start, int N) {
    int lane = threadIdx.x;
    int run = 0;
    for (int b0 = 0; b0 < nb; b0 += 64) {
        int v = (b0 + lane < nb) ? partials[b0 + lane] : 0;
        int s = v;
        #pragma unroll
        for (int d = 1; d < 64; d <<= 1) {
            int u = __shfl_up(s, d, 64);
            if (lane >= d) s += u;
        }
        if (b0 + lane < nb) partials[b0 + lane] = run + s - v;  // exclusive
        run += __shfl(s, 63, 64);
    }
    if (lane == 0) row_start[N] = run;
}

__global__ __launch_bounds__(256) void k_scanC(const int* __restrict__ deg,
        const int* __restrict__ partials, int* __restrict__ row_start, int N) {
    int t = threadIdx.x;
    int base = blockIdx.x * 2048 + t * 8;
    int v[8], s = 0;
    #pragma unroll
    for (int j = 0; j < 8; ++j) { int i = base + j; v[j] = (i < N) ? deg[i] : 0; s += v[j]; }
    int lane = t & 63, w = t >> 6;
    int incl = s;
    #pragma unroll
    for (int d = 1; d < 64; d <<= 1) {
        int u = __shfl_up(incl, d, 64);
        if (lane >= d) incl += u;
    }
    __shared__ int wsum[4];
    if (lane == 63) wsum[w] = incl;
    __syncthreads();
    int woff = 0;
    #pragma unroll
    for (int i = 0; i < 4; ++i) if (i < w) woff += wsum[i];
    int run = partials[blockIdx.x] + woff + incl - s;
    #pragma unroll
    for (int j = 0; j < 8; ++j) {
        int i = base + j;
        if (i < N) row_start[i] = run;
        run += v[j];
    }
}

__global__ __launch_bounds__(256) void k_scatter(const int* __restrict__ ei,
        int E, int E2, const int* __restrict__ row_start, int* __restrict__ cursor,
        int* __restrict__ csr_src) {
    int e = blockIdx.x * 256 + threadIdx.x;
    if (e >= E2) return;
    int src, dst;
    if (e < E) { src = ei[e]; dst = ei[E + e]; }
    else       { src = e - E; dst = src; }
    int pos = row_start[dst] + atomicAdd(&cursor[dst], 1);
    csr_src[pos] = src;
}

// ---------------- GEMM1: [N,512] @ [512,64] -> h1 [N,64] ----------------

__global__ __launch_bounds__(256) void k_gemm1(const float* __restrict__ x,
        const float* __restrict__ W, float* __restrict__ h1, int N) {
    __shared__ float xs[64][17];
    __shared__ float ws[16][64];
    int t = threadIdx.x;
    int row0 = blockIdx.x * 64;
    int c0 = (t & 15) * 4;
    int r0 = (t >> 4) * 4;
    int lr = t >> 2, lf = t & 3;
    int wr = t >> 4, wc = (t & 15) * 4;
    int xrow = min(row0 + lr, N - 1);
    const float* xbase = x + (size_t)xrow * 512 + lf * 4;
    float4 xv = *(const float4*)(xbase);
    float4 wv = *(const float4*)(W + (size_t)wr * 64 + wc);
    float4 acc[4] = {};
    for (int k0 = 0; k0 < 512; k0 += 16) {
        __syncthreads();
        xs[lr][lf * 4 + 0] = xv.x; xs[lr][lf * 4 + 1] = xv.y;
        xs[lr][lf * 4 + 2] = xv.z; xs[lr][lf * 4 + 3] = xv.w;
        *(float4*)&ws[wr][wc] = wv;
        __syncthreads();
        if (k0 + 16 < 512) {
            xv = *(const float4*)(xbase + k0 + 16);
            wv = *(const float4*)(W + (size_t)(k0 + 16 + wr) * 64 + wc);
        }
        #pragma unroll
        for (int kk = 0; kk < 16; ++kk) {
            float4 w4 = *(const float4*)&ws[kk][c0];
            #pragma unroll
            for (int i = 0; i < 4; ++i) {
                float a = xs[r0 + i][kk];
                acc[i].x += a * w4.x; acc[i].y += a * w4.y;
                acc[i].z += a * w4.z; acc[i].w += a * w4.w;
            }
        }
    }
    #pragma unroll
    for (int i = 0; i < 4; ++i) {
        int row = row0 + r0 + i;
        if (row < N) *(float4*)(h1 + (size_t)row * 64 + c0) = acc[i];
    }
}

// ---------------- GEMM2: [N,64] @ [64,128] -> h2 [N,128] ----------------

__global__ __launch_bounds__(256) void k_gemm2(const float* __restrict__ hin,
        const float* __restrict__ W, float* __restrict__ h2, int N) {
    __shared__ float xs[64][65];
    __shared__ float ws[64][128];
    int t = threadIdx.x;
    int row0 = blockIdx.x * 64;
    #pragma unroll
    for (int u = 0; u < 4; ++u) {
        int idx = t + u * 256;
        int r = idx >> 4, f = idx & 15;
        int grow = row0 + r;
        float4 v = make_float4(0.f, 0.f, 0.f, 0.f);
        if (grow < N) v = *(const float4*)(hin + (size_t)grow * 64 + f * 4);
        xs[r][f * 4 + 0] = v.x; xs[r][f * 4 + 1] = v.y;
        xs[r][f * 4 + 2] = v.z; xs[r][f * 4 + 3] = v.w;
    }
    #pragma unroll
    for (int u = 0; u < 8; ++u) {
        int idx = t + u * 256;
        int kr = idx >> 5, c4 = (idx & 31) * 4;
        *(float4*)&ws[kr][c4] = *(const float4*)(W + (size_t)kr * 128 + c4);
    }
    __syncthreads();
    int c0 = (t & 15) * 8;
    int r0 = (t >> 4) * 4;
    float4 acc[4][2] = {};
    #pragma unroll 8
    for (int kk = 0; kk < 64; ++kk) {
        float4 w0 = *(const float4*)&ws[kk][c0];
        float4 w1 = *(const float4*)&ws[kk][c0 + 4];
        #pragma unroll
        for (int i = 0; i < 4; ++i) {
            float a = xs[r0 + i][kk];
            acc[i][0].x += a * w0.x; acc[i][0].y += a * w0.y;
            acc[i][0].z += a * w0.z; acc[i][0].w += a * w0.w;
            acc[i][1].x += a * w1.x; acc[i][1].y += a * w1.y;
            acc[i][1].z += a * w1.z; acc[i][1].w += a * w1.w;
        }
    }
    #pragma unroll
    for (int i = 0; i < 4; ++i) {
        int row = row0 + r0 + i;
        if (row < N) {
            *(float4*)(h2 + (size_t)row * 128 + c0) = acc[i][0];
            *(float4*)(h2 + (size_t)row * 128 + c0 + 4) = acc[i][1];
        }
    }
}

// ---------------- attention coefficients ----------------

__global__ __launch_bounds__(256) void k_att1(const float* __restrict__ h1,
        const float* __restrict__ att_src, const float* __restrict__ att_dst,
        float* __restrict__ a_s, float* __restrict__ a_d, int NH) {
    int i = blockIdx.x * 256 + threadIdx.x;
    if (i >= NH) return;
    int h = i & 7;
    const float* hp = h1 + (size_t)i * 8;
    const float* sp = att_src + h * 8;
    const float* dp = att_dst + h * 8;
    float s = 0.f, d = 0.f;
    #pragma unroll
    for (int c = 0; c < 8; ++c) { float v = hp[c]; s += v * sp[c]; d += v * dp[c]; }
    a_s[i] = s; a_d[i] = d;
}

__global__ __launch_bounds__(256) void k_att2(const float* __restrict__ h2,
        const float* __restrict__ att_src, const float* __restrict__ att_dst,
        float* __restrict__ a_s, float* __restrict__ a_d, int N) {
    int node = blockIdx.x * 4 + (threadIdx.x >> 6);
    int lane = threadIdx.x & 63;
    if (node >= N) return;
    const float* hp = h2 + (size_t)node * 128;
    float v0 = hp[lane], v1 = hp[lane + 64];
    float s = v0 * att_src[lane] + v1 * att_src[lane + 64];
    float d = v0 * att_dst[lane] + v1 * att_dst[lane + 64];
    #pragma unroll
    for (int off = 32; off >= 1; off >>= 1) {
        s += __shfl_xor(s, off, 64);
        d += __shfl_xor(d, off, 64);
    }
    if (lane == 0) { a_s[node] = s; a_d[node] = d; }
}

// ---------------- GAT layer 1 (H=8, C=8), single-pass + bias + ELU ----------------
// One wave per dst node. Per 64-edge chunk: lane j computes the 8 head-weights
// for edge base+j (one 32B gather + 8 exp), stores to per-wave LDS, accumulates
// the denominator; the edge-serial gather loop reads weights from LDS. The
// softmax normalization (acc * 1/den) is applied once at the end.

__global__ __launch_bounds__(256) void k_gat1(
        const int* __restrict__ row_start, const int* __restrict__ csr_src,
        const float* __restrict__ h1,
        const float* __restrict__ a_src, const float* __restrict__ a_dst,
        const float* __restrict__ bias, float* __restrict__ outp, int N) {
    __shared__ float wlds[4][512];            // per-wave weight slab [j*8+h]
    int node = blockIdx.x * 4 + (threadIdx.x >> 6);
    int lane = threadIdx.x & 63;
    if (node >= N) return;
    float* mylds = wlds[threadIdx.x >> 6];
    int h = lane >> 3;
    int start = row_start[node], end = row_start[node + 1];

    float ad8[8];
    #pragma unroll
    for (int hh = 0; hh < 8; ++hh) ad8[hh] = a_dst[(size_t)node * 8 + hh];

    float dh[8] = {0.f,0.f,0.f,0.f,0.f,0.f,0.f,0.f};
    float acc = 0.f;
    for (int base = start; base < end; base += 64) {
        int idx = base + lane;
        int cnt = min(64, end - base);
        int sv = 0;
        if (idx < end) {
            sv = csr_src[idx];
            float4 s0 = *(const float4*)(a_src + (size_t)sv * 8);
            float4 s1 = *(const float4*)(a_src + (size_t)sv * 8 + 4);
            float al[8] = { s0.x + ad8[0], s0.y + ad8[1], s0.z + ad8[2], s0.w + ad8[3],
                            s1.x + ad8[4], s1.y + ad8[5], s1.z + ad8[6], s1.w + ad8[7] };
            float o[8];
            #pragma unroll
            for (int hh = 0; hh < 8; ++hh) {
                float a = al[hh];
                a = a > 0.f ? a : 0.2f * a;
                o[hh] = __expf(a);
                dh[hh] += o[hh];
            }
            *(float4*)&mylds[lane * 8]     = make_float4(o[0], o[1], o[2], o[3]);
            *(float4*)&mylds[lane * 8 + 4] = make_float4(o[4], o[5], o[6], o[7]);
        }
        // edge-serial weighted gather; weights from wave-private LDS
        if (cnt == 64) {
            #pragma unroll 4
            for (int j = 0; j < 64; ++j) {
                int s = __shfl(sv, j, 64);
                float w = mylds[j * 8 + h];
                acc += h1[(size_t)s * 64 + lane] * w;
            }
        } else {
            for (int j = 0; j < cnt; ++j) {
                int s = __shfl(sv, j, 64);
                float w = mylds[j * 8 + h];
                acc += h1[(size_t)s * 64 + lane] * w;
            }
        }
    }
    #pragma unroll
    for (int hh = 0; hh < 8; ++hh) {
        #pragma unroll
        for (int off = 32; off >= 1; off >>= 1) dh[hh] += __shfl_xor(dh[hh], off, 64);
    }
    float den = dh[0];
    #pragma unroll
    for (int hh = 1; hh < 8; ++hh) den = (h == hh) ? dh[hh] : den;
    float inv = 1.f / (den + 1e-16f);
    float v = acc * inv + bias[lane];
    outp[(size_t)node * 64 + lane] = v > 0.f ? v : __expf(v) - 1.f;  // ELU
}

// ---------------- GAT layer 2 (H=1, C=128), single-pass + bias ----------------
// Weights live in registers, broadcast with __shfl; normalize at the end.

__global__ __launch_bounds__(256) void k_gat2(
        const int* __restrict__ row_start, const int* __restrict__ csr_src,
        const float* __restrict__ h2,
        const float* __restrict__ a_src, const float* __restrict__ a_dst,
        const float* __restrict__ bias, float* __restrict__ outp, int N) {
    int node = blockIdx.x * 4 + (threadIdx.x >> 6);
    int lane = threadIdx.x & 63;
    if (node >= N) return;
    int start = row_start[node], end = row_start[node + 1];
    float adst = a_dst[node];

    float dsum = 0.f;
    float acc0 = 0.f, acc1 = 0.f;
    for (int base = start; base < end; base += 64) {
        int idx = base + lane;
        int cnt = min(64, end - base);
        int sv = 0;
        float wv = 0.f;
        if (idx < end) {
            sv = csr_src[idx];
            float a = a_src[sv] + adst;
            a = a > 0.f ? a : 0.2f * a;
            wv = __expf(a);
            dsum += wv;
        }
        if (cnt == 64) {
            #pragma unroll 4
            for (int j = 0; j < 64; ++j) {
                int s = __shfl(sv, j, 64);
                float w = __shfl(wv, j, 64);
                const float* hp = h2 + (size_t)s * 128;
                acc0 += hp[lane] * w;
                acc1 += hp[lane + 64] * w;
            }
        } else {
            for (int j = 0; j < cnt; ++j) {
                int s = __shfl(sv, j, 64);
                float w = __shfl(wv, j, 64);
                const float* hp = h2 + (size_t)s * 128;
                acc0 += hp[lane] * w;
                acc1 += hp[lane + 64] * w;
            }
        }
    }
    #pragma unroll
    for (int off = 32; off >= 1; off >>= 1) dsum += __shfl_xor(dsum, off, 64);
    float inv = 1.f / (dsum + 1e-16f);
    outp[(size_t)node * 128 + lane]      = acc0 * inv + bias[lane];
    outp[(size_t)node * 128 + lane + 64] = acc1 * inv + bias[lane + 64];
}

// ---------------- launcher ----------------

extern "C" void kernel_launch(void* const* d_in, const int* in_sizes, int n_in,
                              void* d_out, int out_size, void* d_ws, size_t ws_size,
                              hipStream_t stream) {
    const float* x   = (const float*)d_in[0];
    const int*   ei  = (const int*)d_in[1];     // integer inputs arrive as int32
    const float* W1  = (const float*)d_in[2];
    const float* as1 = (const float*)d_in[3];
    const float* ad1 = (const float*)d_in[4];
    const float* b1  = (const float*)d_in[5];
    const float* W2  = (const float*)d_in[6];
    const float* as2 = (const float*)d_in[7];
    const float* ad2 = (const float*)d_in[8];
    const float* b2  = (const float*)d_in[9];
    int N  = in_sizes[0] / 512;
    int E  = in_sizes[1] / 2;
    int E2 = E + N;

    char* wsp = (char*)d_ws;
    size_t off = 0;
    auto alloc = [&](size_t bytes) {
        char* p = wsp + off;
        off = (off + bytes + 255) & ~(size_t)255;
        return p;
    };
    float* h1   = (float*)alloc((size_t)N * 64 * 4);
    float* hmid = (float*)alloc((size_t)N * 64 * 4);
    float* h2   = (float*)alloc((size_t)N * 128 * 4);
    float* a1s  = (float*)alloc((size_t)N * 8 * 4);
    float* a1d  = (float*)alloc((size_t)N * 8 * 4);
    float* a2s  = (float*)alloc((size_t)N * 4);
    float* a2d  = (float*)alloc((size_t)N * 4);
    int* deg    = (int*)alloc((size_t)2 * N * 4);  // deg | cursor
    int* cursor = deg + N;
    int* row_start = (int*)alloc((size_t)(N + 1) * 4);
    int* csr_src   = (int*)alloc((size_t)E2 * 4);
    int nbscan = (N + 2047) / 2048;
    int* partials  = (int*)alloc((size_t)nbscan * 4);
    (void)ws_size; (void)n_in; (void)out_size;

    hipMemsetAsync(deg, 0, (size_t)2 * N * 4, stream);
    int eb = (E2 + 255) / 256;
    k_hist<<<eb, 256, 0, stream>>>(ei, E, E2, deg);
    k_scanA<<<nbscan, 256, 0, stream>>>(deg, partials, N);
    k_scanB<<<1, 64, 0, stream>>>(partials, nbscan, row_start, N);
    k_scanC<<<nbscan, 256, 0, stream>>>(deg, partials, row_start, N);
    k_scatter<<<eb, 256, 0, stream>>>(ei, E, E2, row_start, cursor, csr_src);

    int gb = (N + 63) / 64;
    int nb4 = (N + 3) / 4;
    k_gemm1<<<gb, 256, 0, stream>>>(x, W1, h1, N);
    k_att1<<<(N * 8 + 255) / 256, 256, 0, stream>>>(h1, as1, ad1, a1s, a1d, N * 8);
    k_gat1<<<nb4, 256, 0, stream>>>(row_start, csr_src, h1, a1s, a1d, b1, hmid, N);
    k_gemm2<<<gb, 256, 0, stream>>>(hmid, W2, h2, N);
    k_att2<<<nb4, 256, 0, stream>>>(h2, as2, ad2, a2s, a2d, N);
    k_gat2<<<nb4, 256, 0, stream>>>(row_start, csr_src, h2, a2s, a2d, b2, (float*)d_out, N);
}